// Round 7
// baseline (1387.900 us; speedup 1.0000x reference)
//
#include <hip/hip_runtime.h>
#include <hip/hip_bf16.h>
#include <math.h>

#define BB 16
#define LL 4095
#define DD 768
#define TT 768
#define SS 64
#define KK 8
#define HH 384
#define G3 1152   // 3*H
#define NWPD 24   // WGs for the coop scan (each handles BOTH directions)

// ---------- 1. span means (float4) + ctx zero-init (folds a memset node) ----------
__global__ void span_mean_kernel(const float* __restrict__ hidden,
                                 const int* __restrict__ sstart,
                                 const int* __restrict__ slen,
                                 float* __restrict__ span,
                                 float* __restrict__ ctx) {
    // fold: zero ctx (12288 floats) using the first 48 blocks
    if (blockIdx.x < 48) ctx[blockIdx.x * 256 + threadIdx.x] = 0.0f;
    int bs = blockIdx.x;            // b*64+s
    int b = bs >> 6;
    int st = sstart[bs];
    int ln = slen[bs];
    const float4* base = (const float4*)(hidden + ((size_t)b * LL + st) * DD);
    float4* dst = (float4*)(span + (size_t)bs * DD);
    float inv = 1.0f / (float)ln;
    for (int d = threadIdx.x; d < DD / 4; d += 256) {
        float4 acc = make_float4(0.f, 0.f, 0.f, 0.f);
        for (int r = 0; r < ln; ++r) {
            float4 v = base[(size_t)r * (DD / 4) + d];
            acc.x += v.x; acc.y += v.y; acc.z += v.z; acc.w += v.w;
        }
        dst[d] = make_float4(acc.x * inv, acc.y * inv, acc.z * inv, acc.w * inv);
    }
}

// ---------- 2. ctx accumulation (atomic partial sums) ----------
__global__ void ctx_accum_kernel(const float* __restrict__ hidden,
                                 const int* __restrict__ attn_len,
                                 float* __restrict__ ctx) {
    int b = blockIdx.x, chunk = blockIdx.y;
    int lim = attn_len[b] - 1;
    int l0 = chunk * 128;
    int l1 = min(l0 + 128, lim);
    if (l0 >= l1) return;
    int t = threadIdx.x;
    const float* base = hidden + (size_t)b * LL * DD;
    float a0 = 0.f, a1 = 0.f, a2 = 0.f;
    for (int l = l0; l < l1; ++l) {
        const float* row = base + (size_t)l * DD;
        a0 += row[t]; a1 += row[t + 256]; a2 += row[t + 512];
    }
    atomicAdd(&ctx[b * DD + t], a0);
    atomicAdd(&ctx[b * DD + t + 256], a1);
    atomicAdd(&ctx[b * DD + t + 512], a2);
}

// ---------- 3. gi = span @ W_ih^T + b_ih (+ b_hh for r,z gates) ----------
__global__ __launch_bounds__(256) void gi_gemm_kernel(
        const float* __restrict__ span,
        const float* __restrict__ Wf, const float* __restrict__ Wb,
        const float* __restrict__ bihf, const float* __restrict__ bhhf,
        const float* __restrict__ bihb, const float* __restrict__ bhhb,
        float* __restrict__ gi) {
    int dir = blockIdx.z;
    const float* W = dir ? Wb : Wf;
    const float* bih = dir ? bihb : bihf;
    const float* bhh = dir ? bhhb : bhhf;
    int m0 = blockIdx.x * 64, n0 = blockIdx.y * 64;
    __shared__ float As[16][68];   // [k][m]
    __shared__ float Bs[16][68];
    int t = threadIdx.x, tx = t & 15, ty = t >> 4;
    float acc[4][4] = {{0.f}};
    for (int k0 = 0; k0 < DD; k0 += 16) {
        for (int e = t; e < 1024; e += 256) {
            int r = e >> 4, c = e & 15;
            As[c][r] = span[(size_t)(m0 + r) * DD + k0 + c];
            Bs[c][r] = W[(size_t)(n0 + r) * DD + k0 + c];
        }
        __syncthreads();
#pragma unroll
        for (int kk = 0; kk < 16; ++kk) {
            float4 a4 = *(const float4*)&As[kk][ty * 4];
            float4 b4 = *(const float4*)&Bs[kk][tx * 4];
            float a[4] = {a4.x, a4.y, a4.z, a4.w};
            float bv[4] = {b4.x, b4.y, b4.z, b4.w};
#pragma unroll
            for (int i = 0; i < 4; ++i)
#pragma unroll
                for (int j = 0; j < 4; ++j) acc[i][j] += a[i] * bv[j];
        }
        __syncthreads();
    }
#pragma unroll
    for (int i = 0; i < 4; ++i)
#pragma unroll
        for (int j = 0; j < 4; ++j) {
            int m = m0 + ty * 4 + i, n = n0 + tx * 4 + j;
            float v = acc[i][j] + bih[n] + (n < 2 * HH ? bhh[n] : 0.0f);
            gi[((size_t)dir * 1024 + m) * G3 + n] = v;
        }
}

// ---------- 4. rep_context + hpair zero-init (folds a memset node) ----------
// Launched AFTER gi_gemm (span is dead), BEFORE scan: the 48 blocks also
// zero the 24576-u64 hpair region (aliased onto span).
__global__ void repctx_kernel(const float* __restrict__ ctxsum,
                              const int* __restrict__ attn_len,
                              const float* __restrict__ W_ctx,
                              const float* __restrict__ b_ctx,
                              float* __restrict__ out_rc,
                              unsigned long long* __restrict__ hpair) {
    int gid = ((int)blockIdx.y * 16 + (int)blockIdx.x) * 256 + threadIdx.x; // 0..12287
    hpair[gid] = 0ull;
    hpair[gid + 12288] = 0ull;
    int b = blockIdx.x;
    int j = blockIdx.y * 256 + threadIdx.x;
    __shared__ float cv[DD];
    float inv = 1.0f / (float)(attn_len[b] - 1);
    for (int d = threadIdx.x; d < DD; d += 256) cv[d] = ctxsum[b * DD + d] * inv;
    __syncthreads();
    const float* wr = W_ctx + (size_t)j * DD;
    float acc = b_ctx[j];
    for (int d = 0; d < DD; ++d) acc += wr[d] * cv[d];
    out_rc[b * TT + j] = acc;
}

// ---------- 5. GRU coop scan: direction-interleaved, 24 WGs total ----------
// Each WG holds W_hh rows [16w,16w+16) for BOTH directions (144 VGPRs) and
// alternates phase0 (fwd step s) / phase1 (bwd step s) each iteration.
// The two chains are independent: dir0's publish has the whole dir1 phase
// (~1.5-2 us) to reach the coherence point before it is polled next
// iteration, and vice versa -> each tagged-pair poll (R3 protocol,
// known-good) should succeed in ~its first round. Barrier safety: phase1's
// post-poll barrier separates phase0's LDS reads (this iter) from phase0's
// LDS writes (next iter) -- 2 barriers per iteration, none after publish,
// so the agent-scope publish store stays fire-and-forget.
__device__ __forceinline__ void scan_phase(
        int s, int dirp, int p, int kseg, int i_glob, int t,
        const float4 (&wr)[3][6], float bhn,
        const float* __restrict__ gi,
        unsigned long long* __restrict__ hpair,
        float* __restrict__ repac,
        float* hs) {
    const float4* hs4 = (const float4*)hs;
    // gi loads for this thread's output (b = kseg, i_glob), before the poll
    const float* grow = gi + ((size_t)dirp * 1024 + kseg * 64 + p) * G3;
    float g_r = grow[i_glob], g_z = grow[HH + i_glob], g_n = grow[2 * HH + i_glob];
    // poll tagged h pairs: the poll IS the data load (R3-exact)
    {
        const unsigned long long* src = hpair + (size_t)((s & 1) * 2 + dirp) * 6144;
        unsigned int expect = (unsigned int)s;
        unsigned long long vals[24];
        for (;;) {
            bool ok = true;
#pragma unroll
            for (int j = 0; j < 24; ++j) {
                vals[j] = __hip_atomic_load(src + j * 256 + t,
                                            __ATOMIC_RELAXED, __HIP_MEMORY_SCOPE_AGENT);
                ok &= ((unsigned int)(vals[j] >> 32) == expect);
            }
            if (ok) break;
            __builtin_amdgcn_s_sleep(1);
        }
#pragma unroll
        for (int j = 0; j < 24; ++j)
            hs[j * 256 + t] = __uint_as_float((unsigned int)vals[j]);
    }
    __syncthreads();
    // partials for all 16 batches over this thread's k-set
    float pr[16], pz[16], pn[16];
#pragma unroll
    for (int b = 0; b < 16; ++b) {
        float4 hq[6];
#pragma unroll
        for (int j = 0; j < 6; ++j) hq[j] = hs4[b * 96 + kseg + 16 * j];
        float ar = 0.f, az = 0.f, an = 0.f;
#pragma unroll
        for (int j = 0; j < 6; ++j) {
            ar += wr[0][j].x * hq[j].x + wr[0][j].y * hq[j].y + wr[0][j].z * hq[j].z + wr[0][j].w * hq[j].w;
            az += wr[1][j].x * hq[j].x + wr[1][j].y * hq[j].y + wr[1][j].z * hq[j].z + wr[1][j].w * hq[j].w;
            an += wr[2][j].x * hq[j].x + wr[2][j].y * hq[j].y + wr[2][j].z * hq[j].z + wr[2][j].w * hq[j].w;
        }
        pr[b] = ar; pz[b] = az; pn[b] = an;
    }
    // butterfly reduce across the 16 kseg lanes; end: b == kseg
    float qr[8], qz[8], qn[8];
    {
        const bool hi = (kseg & 8) != 0;
#pragma unroll
        for (int j = 0; j < 8; ++j) {
            float sr_ = hi ? pr[j] : pr[j + 8];
            qr[j] = (hi ? pr[j + 8] : pr[j]) + __shfl_xor(sr_, 8);
            float sz_ = hi ? pz[j] : pz[j + 8];
            qz[j] = (hi ? pz[j + 8] : pz[j]) + __shfl_xor(sz_, 8);
            float sn_ = hi ? pn[j] : pn[j + 8];
            qn[j] = (hi ? pn[j + 8] : pn[j]) + __shfl_xor(sn_, 8);
        }
    }
    float ur[4], uz[4], un[4];
    {
        const bool hi = (kseg & 4) != 0;
#pragma unroll
        for (int j = 0; j < 4; ++j) {
            float sr_ = hi ? qr[j] : qr[j + 4];
            ur[j] = (hi ? qr[j + 4] : qr[j]) + __shfl_xor(sr_, 4);
            float sz_ = hi ? qz[j] : qz[j + 4];
            uz[j] = (hi ? qz[j + 4] : qz[j]) + __shfl_xor(sz_, 4);
            float sn_ = hi ? qn[j] : qn[j + 4];
            un[j] = (hi ? qn[j + 4] : qn[j]) + __shfl_xor(sn_, 4);
        }
    }
    float vr[2], vz[2], vn[2];
    {
        const bool hi = (kseg & 2) != 0;
#pragma unroll
        for (int j = 0; j < 2; ++j) {
            float sr_ = hi ? ur[j] : ur[j + 2];
            vr[j] = (hi ? ur[j + 2] : ur[j]) + __shfl_xor(sr_, 2);
            float sz_ = hi ? uz[j] : uz[j + 2];
            vz[j] = (hi ? uz[j + 2] : uz[j]) + __shfl_xor(sz_, 2);
            float sn_ = hi ? un[j] : un[j + 2];
            vn[j] = (hi ? un[j + 2] : un[j]) + __shfl_xor(sn_, 2);
        }
    }
    float sr, sz, sn;
    {
        const bool hi = (kseg & 1) != 0;
        float sr_ = hi ? vr[0] : vr[1];
        sr = (hi ? vr[1] : vr[0]) + __shfl_xor(sr_, 1);
        float sz_ = hi ? vz[0] : vz[1];
        sz = (hi ? vz[1] : vz[0]) + __shfl_xor(sz_, 1);
        float sn_ = hi ? vn[0] : vn[1];
        sn = (hi ? vn[1] : vn[0]) + __shfl_xor(sn_, 1);
    }
    // epilogue: every thread owns one (b = kseg, i_glob) output
    float r = 1.0f / (1.0f + expf(-(g_r + sr)));
    float z = 1.0f / (1.0f + expf(-(g_z + sz)));
    float n = tanhf(g_n + r * (sn + bhn));
    float hold = hs[kseg * 384 + i_glob];
    float hnew = (1.0f - z) * n + z * hold;
    // publish {tag = s+1, h} as one 8-byte relaxed agent store (fire-and-forget)
    unsigned long long pv = ((unsigned long long)(unsigned int)(s + 1) << 32)
                          | (unsigned long long)__float_as_uint(hnew);
    __hip_atomic_store(hpair + (size_t)(((s + 1) & 1) * 2 + dirp) * 6144 + kseg * 384 + i_glob,
                       pv, __ATOMIC_RELAXED, __HIP_MEMORY_SCOPE_AGENT);
    repac[(size_t)(kseg * 64 + p) * TT + dirp * HH + i_glob] = hnew;
}

__global__ __launch_bounds__(256, 1) void scan_coop_kernel(
        const float* __restrict__ gi,
        const float* __restrict__ Whf, const float* __restrict__ Whb,
        const float* __restrict__ bhhf, const float* __restrict__ bhhb,
        unsigned long long* __restrict__ hpair,  // [2 parity][2 dir][16 b][384]
        float* __restrict__ repac) {
    int w = blockIdx.x;             // 0..23
    int t = threadIdx.x;
    int kseg = t & 15, i_loc = t >> 4;
    int i_glob = w * 16 + i_loc;

    // W fragments for BOTH directions (once): 144 VGPRs, asm-pinned
    float4 wr0[3][6], wr1[3][6];
#pragma unroll
    for (int g = 0; g < 3; ++g)
#pragma unroll
        for (int j = 0; j < 6; ++j) {
            wr0[g][j] = *(const float4*)(Whf + (size_t)(g * HH + i_glob) * HH + kseg * 4 + 64 * j);
            asm volatile("" : "+v"(wr0[g][j].x), "+v"(wr0[g][j].y),
                              "+v"(wr0[g][j].z), "+v"(wr0[g][j].w));
            wr1[g][j] = *(const float4*)(Whb + (size_t)(g * HH + i_glob) * HH + kseg * 4 + 64 * j);
            asm volatile("" : "+v"(wr1[g][j].x), "+v"(wr1[g][j].y),
                              "+v"(wr1[g][j].z), "+v"(wr1[g][j].w));
        }
    float bhn0 = bhhf[2 * HH + i_glob];
    float bhn1 = bhhb[2 * HH + i_glob];

    __shared__ __align__(16) float hs0[6144];   // dir0 h-stage [16 b][384]
    __shared__ __align__(16) float hs1[6144];   // dir1 h-stage

    for (int s = 0; s < 64; ++s) {
        scan_phase(s, 0, s,      kseg, i_glob, t, wr0, bhn0, gi, hpair, repac, hs0);
        scan_phase(s, 1, 63 - s, kseg, i_glob, t, wr1, bhn1, gi, hpair, repac, hs1);
    }
}

// ---------- 6. fused find: qk dots + topk + v1 gather (one batch/block) ----------
__global__ __launch_bounds__(256) void find_kernel(
        const float* __restrict__ repac,
        const float* __restrict__ repctx,
        const float* __restrict__ Wfind,
        float* __restrict__ vals_out,
        float* __restrict__ idx_out,
        float* __restrict__ v1) {
    int b = blockIdx.x;             // 0..15
    int t = threadIdx.x;
    int wv = t >> 6, lane = t & 63;
    __shared__ float qs[64];
    __shared__ float ks[65];
    __shared__ int idxs[64 * 8];
    // 1) 129 dot products (64 q + 65 k), fp64 accumulation as before
    for (int j = wv; j < 129; j += 4) {
        bool isq = (j < 64);
        int jj = isq ? j : (j - 64);
        const float* row = isq ? (repac + (size_t)(b * 64 + j) * TT)
                               : ((jj < 64) ? (repac + (size_t)(b * 64 + jj) * TT)
                                            : (repctx + (size_t)b * TT));
        const float* vec = isq ? Wfind : (Wfind + TT);
        double acc = 0.0;
        for (int d = lane; d < TT; d += 64) acc += (double)row[d] * (double)vec[d];
#pragma unroll
        for (int off = 32; off > 0; off >>= 1) acc += __shfl_down(acc, off);
        if (lane == 0) { if (isq) qs[j] = (float)acc; else ks[jj] = (float)acc; }
    }
    __syncthreads();
    // 2) top-k (threads 0..63, one per span; sc[] in registers, full unroll)
    if (t < 64) {
        int bs = b * 64 + t;
        float q = qs[t];
        float sc[65];
#pragma unroll
        for (int j = 0; j < 65; ++j) {
            float x = q + ks[j];                  // fp32 add, as np broadcast-add
            float e = (float)exp(-(double)x);     // ~correctly-rounded f32 exp
            sc[j] = 1.0f / (1.0f + e);            // fp32 add + fp32 divide, as np
        }
        unsigned long long taken = 0ull;
        bool tk64 = false;
        for (int kk = 0; kk < 8; ++kk) {
            float best = -3.0e38f;
            int bj = 0;
#pragma unroll
            for (int j = 0; j < 65; ++j) {
                bool tkn = (j < 64) ? (((taken >> j) & 1ull) != 0ull) : tk64;
                float v = sc[j];
                if (!tkn && v > best) { best = v; bj = j; }  // strict > => lowest idx wins ties
            }
            if (bj < 64) taken |= (1ull << bj); else tk64 = true;
            vals_out[bs * 8 + kk] = best;
            idx_out[bs * 8 + kk] = (float)bj;
            idxs[t * 8 + kk] = bj;
        }
    }
    __syncthreads();
    // 3) v1 gather: 512 row-copies of 768 floats (float4), one wave per copy
    for (int c = wv; c < 512; c += 4) {
        int s = c >> 3, kk = c & 7;
        int j = idxs[s * 8 + kk];
        const float4* src = (const float4*)((j < 64) ? (repac + (size_t)(b * 64 + j) * TT)
                                                     : (repctx + (size_t)b * TT));
        float4* dst = (float4*)(v1 + ((size_t)(b * 64 + s) * 8 + kk) * TT);
        for (int d = lane; d < TT / 4; d += 64) dst[d] = src[d];
    }
}

extern "C" void kernel_launch(void* const* d_in, const int* in_sizes, int n_in,
                              void* d_out, int out_size, void* d_ws, size_t ws_size,
                              hipStream_t stream) {
    const float* hidden    = (const float*)d_in[0];
    const float* W_ih_f    = (const float*)d_in[1];
    const float* W_hh_f    = (const float*)d_in[2];
    const float* b_ih_f    = (const float*)d_in[3];
    const float* b_hh_f    = (const float*)d_in[4];
    const float* W_ih_b    = (const float*)d_in[5];
    const float* W_hh_b    = (const float*)d_in[6];
    const float* b_ih_b    = (const float*)d_in[7];
    const float* b_hh_b    = (const float*)d_in[8];
    const float* W_ctx     = (const float*)d_in[9];
    const float* b_ctx     = (const float*)d_in[10];
    const float* W_find    = (const float*)d_in[11];
    const int*   attn_len  = (const int*)d_in[12];
    const int*   span_start= (const int*)d_in[13];
    const int*   span_len  = (const int*)d_in[14];
    (void)in_sizes; (void)n_in; (void)out_size; (void)ws_size;

    // workspace layout (floats)
    float* ws   = (float*)d_ws;
    float* span = ws;                       // 786432
    float* gi   = span + 786432;            // 2359296
    float* ctx  = gi + 2359296;             // 12288
    // hpair ALIASES the span region (span is dead after gi_gemm; zeroed by
    // repctx_kernel, which runs between gi_gemm and scan). 24576 u64 = 192 KiB.
    unsigned long long* hpair = (unsigned long long*)span;

    // output layout (floats)
    float* out      = (float*)d_out;
    float* o_repac  = out;                  // 786432
    float* o_repctx = out + 786432;         // 12288
    float* o_v1     = out + 798720;         // 6291456
    float* o_vals   = out + 7090176;        // 8192
    float* o_idx    = out + 7098368;        // 8192

    // 6 nodes total (was 10): memsets folded into span_mean / repctx,
    // qkv+topk+v1 fused into find_kernel.
    span_mean_kernel<<<1024, 256, 0, stream>>>(hidden, span_start, span_len, span, ctx);
    ctx_accum_kernel<<<dim3(BB, 32), 256, 0, stream>>>(hidden, attn_len, ctx);
    gi_gemm_kernel<<<dim3(16, 18, 2), 256, 0, stream>>>(span, W_ih_f, W_ih_b,
                                                        b_ih_f, b_hh_f, b_ih_b, b_hh_b, gi);
    repctx_kernel<<<dim3(BB, 3), 256, 0, stream>>>(ctx, attn_len, W_ctx, b_ctx,
                                                   o_repctx, hpair);
    scan_coop_kernel<<<NWPD, 256, 0, stream>>>(gi, W_hh_f, W_hh_b, b_hh_f, b_hh_b,
                                               hpair, o_repac);
    find_kernel<<<BB, 256, 0, stream>>>(o_repac, o_repctx, W_find,
                                        o_vals, o_idx, o_v1);
}

// Round 8
// 1308.255 us; speedup vs baseline: 1.0609x; 1.0609x over previous
//
#include <hip/hip_runtime.h>
#include <hip/hip_bf16.h>
#include <math.h>

#define BB 16
#define LL 4095
#define DD 768
#define TT 768
#define SS 64
#define KK 8
#define HH 384
#define G3 1152    // 3*H
#define NWPD 24    // WGs per direction for the coop scan
#define NWORK 48   // total scan workers (24 per dir), elected onto ONE XCD

// ---------- 1. span means (float4) + ctx zero-init ----------
__global__ void span_mean_kernel(const float* __restrict__ hidden,
                                 const int* __restrict__ sstart,
                                 const int* __restrict__ slen,
                                 float* __restrict__ span,
                                 float* __restrict__ ctx) {
    if (blockIdx.x < 48) ctx[blockIdx.x * 256 + threadIdx.x] = 0.0f;
    int bs = blockIdx.x;            // b*64+s
    int b = bs >> 6;
    int st = sstart[bs];
    int ln = slen[bs];
    const float4* base = (const float4*)(hidden + ((size_t)b * LL + st) * DD);
    float4* dst = (float4*)(span + (size_t)bs * DD);
    float inv = 1.0f / (float)ln;
    for (int d = threadIdx.x; d < DD / 4; d += 256) {
        float4 acc = make_float4(0.f, 0.f, 0.f, 0.f);
        for (int r = 0; r < ln; ++r) {
            float4 v = base[(size_t)r * (DD / 4) + d];
            acc.x += v.x; acc.y += v.y; acc.z += v.z; acc.w += v.w;
        }
        dst[d] = make_float4(acc.x * inv, acc.y * inv, acc.z * inv, acc.w * inv);
    }
}

// ---------- 2. ctx accumulation (atomic partial sums) ----------
__global__ void ctx_accum_kernel(const float* __restrict__ hidden,
                                 const int* __restrict__ attn_len,
                                 float* __restrict__ ctx) {
    int b = blockIdx.x, chunk = blockIdx.y;
    int lim = attn_len[b] - 1;
    int l0 = chunk * 128;
    int l1 = min(l0 + 128, lim);
    if (l0 >= l1) return;
    int t = threadIdx.x;
    const float* base = hidden + (size_t)b * LL * DD;
    float a0 = 0.f, a1 = 0.f, a2 = 0.f;
    for (int l = l0; l < l1; ++l) {
        const float* row = base + (size_t)l * DD;
        a0 += row[t]; a1 += row[t + 256]; a2 += row[t + 512];
    }
    atomicAdd(&ctx[b * DD + t], a0);
    atomicAdd(&ctx[b * DD + t + 256], a1);
    atomicAdd(&ctx[b * DD + t + 512], a2);
}

// ---------- 3. fused: gi GEMM (blocks 0..575) + repctx & scan-buffer zero (576..623) ----------
__global__ __launch_bounds__(256) void fused_b_kernel(
        const float* __restrict__ span,
        const float* __restrict__ Wf, const float* __restrict__ Wb,
        const float* __restrict__ bihf, const float* __restrict__ bhhf,
        const float* __restrict__ bihb, const float* __restrict__ bhhb,
        float* __restrict__ gi,
        const float* __restrict__ ctxsum, const int* __restrict__ attn_len,
        const float* __restrict__ W_ctx, const float* __restrict__ b_ctx,
        float* __restrict__ out_rc,
        unsigned long long* __restrict__ hpair,
        unsigned long long* __restrict__ mirror,
        int* __restrict__ elect) {
    int bid = blockIdx.x;
    int t = threadIdx.x;
    if (bid < 576) {
        // ---- gi = span @ W_ih^T + b_ih (+ b_hh for r,z gates) ----
        int mb = bid & 15, nb = (bid >> 4) % 18, dir = bid / 288;
        const float* W = dir ? Wb : Wf;
        const float* bih = dir ? bihb : bihf;
        const float* bhh = dir ? bhhb : bhhf;
        int m0 = mb * 64, n0 = nb * 64;
        __shared__ float As[16][68];   // [k][m]
        __shared__ float Bs[16][68];
        int tx = t & 15, ty = t >> 4;
        float acc[4][4] = {{0.f}};
        for (int k0 = 0; k0 < DD; k0 += 16) {
            for (int e = t; e < 1024; e += 256) {
                int r = e >> 4, c = e & 15;
                As[c][r] = span[(size_t)(m0 + r) * DD + k0 + c];
                Bs[c][r] = W[(size_t)(n0 + r) * DD + k0 + c];
            }
            __syncthreads();
#pragma unroll
            for (int kk = 0; kk < 16; ++kk) {
                float4 a4 = *(const float4*)&As[kk][ty * 4];
                float4 b4 = *(const float4*)&Bs[kk][tx * 4];
                float a[4] = {a4.x, a4.y, a4.z, a4.w};
                float bv[4] = {b4.x, b4.y, b4.z, b4.w};
#pragma unroll
                for (int i = 0; i < 4; ++i)
#pragma unroll
                    for (int j = 0; j < 4; ++j) acc[i][j] += a[i] * bv[j];
            }
            __syncthreads();
        }
#pragma unroll
        for (int i = 0; i < 4; ++i)
#pragma unroll
            for (int j = 0; j < 4; ++j) {
                int m = m0 + ty * 4 + i, n = n0 + tx * 4 + j;
                float v = acc[i][j] + bih[n] + (n < 2 * HH ? bhh[n] : 0.0f);
                gi[((size_t)dir * 1024 + m) * G3 + n] = v;
            }
    } else {
        // ---- zero hpair + mirror + elect (scan protocol state), then rep_context ----
        int rb = bid - 576;            // 0..47
        int gid = rb * 256 + t;        // 0..12287
        hpair[gid] = 0ull;  hpair[gid + 12288] = 0ull;
        mirror[gid] = 0ull; mirror[gid + 12288] = 0ull;
        if (rb == 0 && t < 16) elect[t] = 0;
        int b = rb & 15;
        int j = (rb >> 4) * 256 + t;
        __shared__ float cv[DD];
        float inv = 1.0f / (float)(attn_len[b] - 1);
        for (int d = t; d < DD; d += 256) cv[d] = ctxsum[b * DD + d] * inv;
        __syncthreads();
        const float* wr = W_ctx + (size_t)j * DD;
        float acc = b_ctx[j];
        for (int d = 0; d < DD; ++d) acc += wr[d] * cv[d];
        out_rc[b * TT + j] = acc;
    }
}

// ---------- 4. GRU coop scan: single-XCD election + L2-point sync ----------
// The R3/R5 tagged-pair protocol's ~5 us/step residual is detect cost at the
// MALL (agent scope): ~0.4-0.5 us poll rounds + convoy over 48 WGs (R7 proved
// it is NOT publish-visibility: interposing a whole phase didn't shrink it).
// Fix: put all 48 workers on ONE XCD so the shared L2 is the coherence point.
//  - Launch 768 WGs (>=2/CU co-resident via launch_bounds -> >=512 resident ->
//    pigeonhole >=64 on some XCD). Elect the first XCD to accumulate 48
//    arrivals (agent-scope counters); its first 48 ranks work, rest exit.
//  - Publish: workgroup-scope 8B atomic store (write-through to local L2)
//    PLUS an agent-scope MALL mirror store (fallback correctness).
//  - Poll fast path: inline-asm global_load_dwordx2 sc0 (bypass L1, serve
//    from L2, ~250cy) + vmcnt(0) + sched_barrier (rule #18). Every 8 failed
//    rounds: one agent-scope round on the mirror -> if election/sc0/placement
//    assumptions ever fail, degrades to ~R5 speed instead of hanging.
//  - Barriers: lgkmcnt(0) + raw s_barrier (no vmcnt drain; the next poll's
//    vmcnt(0) overlaps store-acks with its own load latency).
__global__ __launch_bounds__(256, 2) void scan_coop_kernel(
        const float* __restrict__ gi,
        const float* __restrict__ Whf, const float* __restrict__ Whb,
        const float* __restrict__ bhhf, const float* __restrict__ bhhb,
        unsigned long long* __restrict__ hpair,   // [2 parity][2 dir][16 b][384]
        unsigned long long* __restrict__ mirror,  // same layout, MALL copy
        int* __restrict__ elect,                  // [8] cnt + [8] winner(+1)
        float* __restrict__ repac) {
    __shared__ int sh_widx;
    int t = threadIdx.x;
    if (t == 0) {
        int xcd = __builtin_amdgcn_s_getreg((3 << 11) | 20) & 7;  // HW_REG_XCC_ID[3:0]
        int rank = __hip_atomic_fetch_add(&elect[xcd], 1,
                                          __ATOMIC_RELAXED, __HIP_MEMORY_SCOPE_AGENT);
        if (rank == NWORK - 1) {
            int exp0 = 0;
            __hip_atomic_compare_exchange_strong(&elect[8], &exp0, xcd + 1,
                __ATOMIC_RELAXED, __ATOMIC_RELAXED, __HIP_MEMORY_SCOPE_AGENT);
        }
        int wnr;
        for (;;) {
            wnr = __hip_atomic_load(&elect[8], __ATOMIC_RELAXED, __HIP_MEMORY_SCOPE_AGENT);
            if (wnr != 0) break;
            __builtin_amdgcn_s_sleep(8);
        }
        sh_widx = (wnr == xcd + 1 && rank < NWORK) ? rank : -1;
    }
    __syncthreads();
    int widx = sh_widx;
    if (widx < 0) return;

    int dir = widx / NWPD;
    int w = widx % NWPD;
    int kseg = t & 15, i_loc = t >> 4;
    int i_glob = w * 16 + i_loc;
    const float* Wh = dir ? Whb : Whf;

    // W fragments into registers (once); per-scalar asm pin keeps them resident
    float4 wr[3][6];
#pragma unroll
    for (int g = 0; g < 3; ++g)
#pragma unroll
        for (int j = 0; j < 6; ++j) {
            wr[g][j] = *(const float4*)(Wh + (size_t)(g * HH + i_glob) * HH + kseg * 4 + 64 * j);
            asm volatile("" : "+v"(wr[g][j].x), "+v"(wr[g][j].y),
                              "+v"(wr[g][j].z), "+v"(wr[g][j].w));
        }
    float bhn = (dir ? bhhb : bhhf)[2 * HH + i_glob];

    __shared__ __align__(16) float hs[6144];          // [16 b][384]
    float4* hs4 = (float4*)hs;

    for (int s = 0; s < 64; ++s) {
        int p = dir ? (63 - s) : s;
        // gi loads for this thread's output; issued before the poll
        const float* grow = gi + ((size_t)dir * 1024 + kseg * 64 + p) * G3;
        float g_r = grow[i_glob], g_z = grow[HH + i_glob], g_n = grow[2 * HH + i_glob];
        // ---- poll tagged pairs: fast sc0/L2 path + periodic MALL fallback ----
        {
            const unsigned long long* src  = hpair  + (size_t)((s & 1) * 2 + dir) * 6144;
            const unsigned long long* msrc = mirror + (size_t)((s & 1) * 2 + dir) * 6144;
            unsigned int expect = (unsigned int)s;
            unsigned long long vals[24];
            int rounds = 0;
            for (;;) {
#pragma unroll
                for (int j = 0; j < 24; ++j) {
                    unsigned int off = (unsigned int)((j * 256 + t) * 8);
                    asm volatile("global_load_dwordx2 %0, %1, %2 sc0"
                                 : "=v"(vals[j]) : "v"(off), "s"(src));
                }
                asm volatile("s_waitcnt vmcnt(0)" ::: "memory");
                __builtin_amdgcn_sched_barrier(0);
                bool ok = true;
#pragma unroll
                for (int j = 0; j < 24; ++j) ok &= ((unsigned int)(vals[j] >> 32) == expect);
                if (ok) break;
                if (((++rounds) & 7) == 0) {   // fallback: MALL mirror round
                    bool mok = true;
#pragma unroll
                    for (int j = 0; j < 24; ++j) {
                        vals[j] = __hip_atomic_load(msrc + j * 256 + t,
                                                    __ATOMIC_RELAXED, __HIP_MEMORY_SCOPE_AGENT);
                        mok &= ((unsigned int)(vals[j] >> 32) == expect);
                    }
                    if (mok) break;
                }
                __builtin_amdgcn_s_sleep(1);
            }
#pragma unroll
            for (int j = 0; j < 24; ++j)
                hs[j * 256 + t] = __uint_as_float((unsigned int)vals[j]);
        }
        // LDS-only barrier (no global-store drain)
        asm volatile("s_waitcnt lgkmcnt(0)" ::: "memory");
        __builtin_amdgcn_sched_barrier(0);
        __builtin_amdgcn_s_barrier();
        // ---- partials for all 16 batches over this thread's k-set ----
        float pr[16], pz[16], pn[16];
#pragma unroll
        for (int b = 0; b < 16; ++b) {
            float4 hq[6];
#pragma unroll
            for (int j = 0; j < 6; ++j) hq[j] = hs4[b * 96 + kseg + 16 * j];
            float ar = 0.f, az = 0.f, an = 0.f;
#pragma unroll
            for (int j = 0; j < 6; ++j) {
                ar += wr[0][j].x * hq[j].x + wr[0][j].y * hq[j].y + wr[0][j].z * hq[j].z + wr[0][j].w * hq[j].w;
                az += wr[1][j].x * hq[j].x + wr[1][j].y * hq[j].y + wr[1][j].z * hq[j].z + wr[1][j].w * hq[j].w;
                an += wr[2][j].x * hq[j].x + wr[2][j].y * hq[j].y + wr[2][j].z * hq[j].z + wr[2][j].w * hq[j].w;
            }
            pr[b] = ar; pz[b] = az; pn[b] = an;
        }
        // ---- butterfly reduce across the 16 kseg lanes; end: b == kseg ----
        float qr[8], qz[8], qn[8];
        {
            const bool hi = (kseg & 8) != 0;
#pragma unroll
            for (int j = 0; j < 8; ++j) {
                float sr_ = hi ? pr[j] : pr[j + 8];
                qr[j] = (hi ? pr[j + 8] : pr[j]) + __shfl_xor(sr_, 8);
                float sz_ = hi ? pz[j] : pz[j + 8];
                qz[j] = (hi ? pz[j + 8] : pz[j]) + __shfl_xor(sz_, 8);
                float sn_ = hi ? pn[j] : pn[j + 8];
                qn[j] = (hi ? pn[j + 8] : pn[j]) + __shfl_xor(sn_, 8);
            }
        }
        float ur[4], uz[4], un[4];
        {
            const bool hi = (kseg & 4) != 0;
#pragma unroll
            for (int j = 0; j < 4; ++j) {
                float sr_ = hi ? qr[j] : qr[j + 4];
                ur[j] = (hi ? qr[j + 4] : qr[j]) + __shfl_xor(sr_, 4);
                float sz_ = hi ? qz[j] : qz[j + 4];
                uz[j] = (hi ? qz[j + 4] : qz[j]) + __shfl_xor(sz_, 4);
                float sn_ = hi ? qn[j] : qn[j + 4];
                un[j] = (hi ? qn[j + 4] : qn[j]) + __shfl_xor(sn_, 4);
            }
        }
        float vr[2], vz[2], vn[2];
        {
            const bool hi = (kseg & 2) != 0;
#pragma unroll
            for (int j = 0; j < 2; ++j) {
                float sr_ = hi ? ur[j] : ur[j + 2];
                vr[j] = (hi ? ur[j + 2] : ur[j]) + __shfl_xor(sr_, 2);
                float sz_ = hi ? uz[j] : uz[j + 2];
                vz[j] = (hi ? uz[j + 2] : uz[j]) + __shfl_xor(sz_, 2);
                float sn_ = hi ? un[j] : un[j + 2];
                vn[j] = (hi ? un[j + 2] : un[j]) + __shfl_xor(sn_, 2);
            }
        }
        float sr, sz, sn;
        {
            const bool hi = (kseg & 1) != 0;
            float sr_ = hi ? vr[0] : vr[1];
            sr = (hi ? vr[1] : vr[0]) + __shfl_xor(sr_, 1);
            float sz_ = hi ? vz[0] : vz[1];
            sz = (hi ? vz[1] : vz[0]) + __shfl_xor(sz_, 1);
            float sn_ = hi ? vn[0] : vn[1];
            sn = (hi ? vn[1] : vn[0]) + __shfl_xor(sn_, 1);
        }
        // ---- epilogue: every thread owns one (b = kseg, i_glob) output ----
        float r = 1.0f / (1.0f + expf(-(g_r + sr)));
        float z = 1.0f / (1.0f + expf(-(g_z + sz)));
        float n = tanhf(g_n + r * (sn + bhn));
        float hold = hs[kseg * 384 + i_glob];
        float hnew = (1.0f - z) * n + z * hold;
        unsigned long long pv = ((unsigned long long)(unsigned int)(s + 1) << 32)
                              | (unsigned long long)__float_as_uint(hnew);
        size_t pidx = (size_t)(((s + 1) & 1) * 2 + dir) * 6144 + kseg * 384 + i_glob;
        // L2 publish (same-XCD fast path): workgroup-scope 8B store, un-torn
        __hip_atomic_store(hpair + pidx, pv, __ATOMIC_RELAXED, __HIP_MEMORY_SCOPE_WORKGROUP);
        // MALL mirror (fallback correctness under any placement)
        __hip_atomic_store(mirror + pidx, pv, __ATOMIC_RELAXED, __HIP_MEMORY_SCOPE_AGENT);
        repac[(size_t)(kseg * 64 + p) * TT + dir * HH + i_glob] = hnew;
        // end LDS-only barrier (protect hs before next step's stage writes)
        asm volatile("s_waitcnt lgkmcnt(0)" ::: "memory");
        __builtin_amdgcn_sched_barrier(0);
        __builtin_amdgcn_s_barrier();
    }
}

// ---------- 5. q and k dot products (one wave each, fp64 accumulation) ----------
__global__ void qkv_kernel(const float* __restrict__ repac,
                           const float* __restrict__ repctx,
                           const float* __restrict__ Wfind,
                           float* __restrict__ qv, float* __restrict__ kv) {
    int w = blockIdx.x * 4 + (threadIdx.x >> 6);
    int lane = threadIdx.x & 63;
    const float* row;
    const float* vec;
    float* dst;
    if (w < 1024) {
        row = repac + (size_t)w * TT;
        vec = Wfind;
        dst = qv + w;
    } else {
        int u = w - 1024;
        int b = u / 65, j = u % 65;
        row = (j < 64) ? (repac + (size_t)(b * 64 + j) * TT) : (repctx + (size_t)b * TT);
        vec = Wfind + TT;
        dst = kv + u;
    }
    double acc = 0.0;
    for (int d = lane; d < TT; d += 64) acc += (double)row[d] * (double)vec[d];
#pragma unroll
    for (int off = 32; off > 0; off >>= 1) acc += __shfl_down(acc, off);
    if (lane == 0) *dst = (float)acc;
}

// ---------- 6. top-k: fully-unrolled (sc[] in registers), one batch/block ----------
__global__ __launch_bounds__(64) void topk_kernel(
                            const float* __restrict__ qv,
                            const float* __restrict__ kv,
                            float* __restrict__ vals_out,
                            float* __restrict__ idx_out,
                            int* __restrict__ idxw) {
    int t = threadIdx.x;            // 0..63
    int b = blockIdx.x;             // batch
    int bs = b * 64 + t;
    __shared__ float kvs[65];
    for (int e = t; e < 65; e += 64) kvs[e] = kv[b * 65 + e];
    __syncthreads();
    float q = qv[bs];
    float sc[65];
#pragma unroll
    for (int j = 0; j < 65; ++j) {
        float x = q + kvs[j];                 // fp32 add, as np broadcast-add
        float e = (float)exp(-(double)x);     // ~correctly-rounded f32 exp
        sc[j] = 1.0f / (1.0f + e);            // fp32 add + fp32 divide, as np
    }
    unsigned long long taken = 0ull;
    bool tk64 = false;
    for (int kk = 0; kk < 8; ++kk) {
        float best = -3.0e38f;
        int bj = 0;
#pragma unroll
        for (int j = 0; j < 65; ++j) {
            bool tkn = (j < 64) ? (((taken >> j) & 1ull) != 0ull) : tk64;
            float v = sc[j];
            if (!tkn && v > best) { best = v; bj = j; }   // strict > => lowest index wins ties
        }
        if (bj < 64) taken |= (1ull << bj); else tk64 = true;
        vals_out[bs * 8 + kk] = best;
        idx_out[bs * 8 + kk] = (float)bj;
        idxw[bs * 8 + kk] = bj;
    }
}

// ---------- 7. v1 gather (float4) ----------
__global__ void v1_kernel(const float* __restrict__ repac,
                          const float* __restrict__ repctx,
                          const int* __restrict__ idxw,
                          float* __restrict__ v1) {
    int bs = blockIdx.x;
    int b = bs >> 6;
    int t = threadIdx.x;
    for (int kk = 0; kk < 8; ++kk) {
        int j = idxw[bs * 8 + kk];
        const float4* src = (const float4*)((j < 64) ? (repac + (size_t)(b * 64 + j) * TT)
                                                     : (repctx + (size_t)b * TT));
        float4* dst = (float4*)(v1 + ((size_t)bs * 8 + kk) * TT);
        for (int d = t; d < DD / 4; d += 256) dst[d] = src[d];
    }
}

extern "C" void kernel_launch(void* const* d_in, const int* in_sizes, int n_in,
                              void* d_out, int out_size, void* d_ws, size_t ws_size,
                              hipStream_t stream) {
    const float* hidden    = (const float*)d_in[0];
    const float* W_ih_f    = (const float*)d_in[1];
    const float* W_hh_f    = (const float*)d_in[2];
    const float* b_ih_f    = (const float*)d_in[3];
    const float* b_hh_f    = (const float*)d_in[4];
    const float* W_ih_b    = (const float*)d_in[5];
    const float* W_hh_b    = (const float*)d_in[6];
    const float* b_ih_b    = (const float*)d_in[7];
    const float* b_hh_b    = (const float*)d_in[8];
    const float* W_ctx     = (const float*)d_in[9];
    const float* b_ctx     = (const float*)d_in[10];
    const float* W_find    = (const float*)d_in[11];
    const int*   attn_len  = (const int*)d_in[12];
    const int*   span_start= (const int*)d_in[13];
    const int*   span_len  = (const int*)d_in[14];
    (void)in_sizes; (void)n_in; (void)out_size; (void)ws_size;

    // workspace layout (floats)
    float* ws   = (float*)d_ws;
    float* span = ws;                       // 786432
    float* gi   = span + 786432;            // 2359296
    float* ctx  = gi + 2359296;             // 12288
    float* qv   = ctx + 12288;              // 1024
    float* kv   = qv + 1024;                // 1040
    int*   idxw = (int*)(kv + 1040);        // 8192

    // output layout (floats)
    float* out      = (float*)d_out;
    float* o_repac  = out;                  // 786432
    float* o_repctx = out + 786432;         // 12288
    float* o_v1     = out + 798720;         // 6291456
    float* o_vals   = out + 7090176;        // 8192
    float* o_idx    = out + 7098368;        // 8192

    // scan protocol state ALIASES the head of o_v1 (dead until v1_kernel,
    // which fully overwrites it). Zeroed every replay by fused_b_kernel.
    // hpair: 24576 u64 (=49152 f), mirror: 24576 u64, elect: 16 ints.
    unsigned long long* hpair  = (unsigned long long*)o_v1;
    unsigned long long* mirror = hpair + 24576;
    int* elect = (int*)(mirror + 24576);

    // 7 nodes, zero memsets.
    span_mean_kernel<<<1024, 256, 0, stream>>>(hidden, span_start, span_len, span, ctx);
    ctx_accum_kernel<<<dim3(BB, 32), 256, 0, stream>>>(hidden, attn_len, ctx);
    fused_b_kernel<<<624, 256, 0, stream>>>(span, W_ih_f, W_ih_b,
                                            b_ih_f, b_hh_f, b_ih_b, b_hh_b, gi,
                                            ctx, attn_len, W_ctx, b_ctx,
                                            o_repctx, hpair, mirror, elect);
    scan_coop_kernel<<<768, 256, 0, stream>>>(gi, W_hh_f, W_hh_b, b_hh_f, b_hh_b,
                                              hpair, mirror, elect, o_repac);
    qkv_kernel<<<516, 256, 0, stream>>>(o_repac, o_repctx, W_find, qv, kv);
    topk_kernel<<<16, 64, 0, stream>>>(qv, kv, o_vals, o_idx, idxw);
    v1_kernel<<<1024, 256, 0, stream>>>(o_repac, o_repctx, idxw, o_v1);
}

// Round 9
// 878.174 us; speedup vs baseline: 1.5804x; 1.4897x over previous
//
#include <hip/hip_runtime.h>
#include <hip/hip_bf16.h>
#include <math.h>

#define BB 16
#define LL 4095
#define DD 768
#define TT 768
#define SS 64
#define KK 8
#define HH 384
#define G3 1152   // 3*H
#define NWPD 24   // WGs per direction for the coop scan

// ---------- 1. span means (float4) + ctx zero-init ----------
__global__ void span_mean_kernel(const float* __restrict__ hidden,
                                 const int* __restrict__ sstart,
                                 const int* __restrict__ slen,
                                 float* __restrict__ span,
                                 float* __restrict__ ctx) {
    if (blockIdx.x < 48) ctx[blockIdx.x * 256 + threadIdx.x] = 0.0f;
    int bs = blockIdx.x;            // b*64+s
    int b = bs >> 6;
    int st = sstart[bs];
    int ln = slen[bs];
    const float4* base = (const float4*)(hidden + ((size_t)b * LL + st) * DD);
    float4* dst = (float4*)(span + (size_t)bs * DD);
    float inv = 1.0f / (float)ln;
    for (int d = threadIdx.x; d < DD / 4; d += 256) {
        float4 acc = make_float4(0.f, 0.f, 0.f, 0.f);
        for (int r = 0; r < ln; ++r) {
            float4 v = base[(size_t)r * (DD / 4) + d];
            acc.x += v.x; acc.y += v.y; acc.z += v.z; acc.w += v.w;
        }
        dst[d] = make_float4(acc.x * inv, acc.y * inv, acc.z * inv, acc.w * inv);
    }
}

// ---------- 2. ctx accumulation (atomic partial sums) ----------
__global__ void ctx_accum_kernel(const float* __restrict__ hidden,
                                 const int* __restrict__ attn_len,
                                 float* __restrict__ ctx) {
    int b = blockIdx.x, chunk = blockIdx.y;
    int lim = attn_len[b] - 1;
    int l0 = chunk * 128;
    int l1 = min(l0 + 128, lim);
    if (l0 >= l1) return;
    int t = threadIdx.x;
    const float* base = hidden + (size_t)b * LL * DD;
    float a0 = 0.f, a1 = 0.f, a2 = 0.f;
    for (int l = l0; l < l1; ++l) {
        const float* row = base + (size_t)l * DD;
        a0 += row[t]; a1 += row[t + 256]; a2 += row[t + 512];
    }
    atomicAdd(&ctx[b * DD + t], a0);
    atomicAdd(&ctx[b * DD + t + 256], a1);
    atomicAdd(&ctx[b * DD + t + 512], a2);
}

// ---------- 3. fused: gi GEMM (blocks 0..575) + repctx & hpair zero (576..623) ----------
__global__ __launch_bounds__(256) void fused_b_kernel(
        const float* __restrict__ span,
        const float* __restrict__ Wf, const float* __restrict__ Wb,
        const float* __restrict__ bihf, const float* __restrict__ bhhf,
        const float* __restrict__ bihb, const float* __restrict__ bhhb,
        float* __restrict__ gi,
        const float* __restrict__ ctxsum, const int* __restrict__ attn_len,
        const float* __restrict__ W_ctx, const float* __restrict__ b_ctx,
        float* __restrict__ out_rc,
        unsigned long long* __restrict__ hpair) {
    int bid = blockIdx.x;
    int t = threadIdx.x;
    if (bid < 576) {
        // ---- gi = span @ W_ih^T + b_ih (+ b_hh for r,z gates) ----
        int mb = bid & 15, nb = (bid >> 4) % 18, dir = bid / 288;
        const float* W = dir ? Wb : Wf;
        const float* bih = dir ? bihb : bihf;
        const float* bhh = dir ? bhhb : bhhf;
        int m0 = mb * 64, n0 = nb * 64;
        __shared__ float As[16][68];   // [k][m]
        __shared__ float Bs[16][68];
        int tx = t & 15, ty = t >> 4;
        float acc[4][4] = {{0.f}};
        for (int k0 = 0; k0 < DD; k0 += 16) {
            for (int e = t; e < 1024; e += 256) {
                int r = e >> 4, c = e & 15;
                As[c][r] = span[(size_t)(m0 + r) * DD + k0 + c];
                Bs[c][r] = W[(size_t)(n0 + r) * DD + k0 + c];
            }
            __syncthreads();
#pragma unroll
            for (int kk = 0; kk < 16; ++kk) {
                float4 a4 = *(const float4*)&As[kk][ty * 4];
                float4 b4 = *(const float4*)&Bs[kk][tx * 4];
                float a[4] = {a4.x, a4.y, a4.z, a4.w};
                float bv[4] = {b4.x, b4.y, b4.z, b4.w};
#pragma unroll
                for (int i = 0; i < 4; ++i)
#pragma unroll
                    for (int j = 0; j < 4; ++j) acc[i][j] += a[i] * bv[j];
            }
            __syncthreads();
        }
#pragma unroll
        for (int i = 0; i < 4; ++i)
#pragma unroll
            for (int j = 0; j < 4; ++j) {
                int m = m0 + ty * 4 + i, n = n0 + tx * 4 + j;
                float v = acc[i][j] + bih[n] + (n < 2 * HH ? bhh[n] : 0.0f);
                gi[((size_t)dir * 1024 + m) * G3 + n] = v;
            }
    } else {
        // ---- zero hpair (scan protocol state: h0 = 0, tag = 0), then rep_context ----
        int rb = bid - 576;            // 0..47
        int gid = rb * 256 + t;        // 0..12287
        hpair[gid] = 0ull;
        hpair[gid + 12288] = 0ull;
        int b = rb & 15;
        int j = (rb >> 4) * 256 + t;
        __shared__ float cv[DD];
        float inv = 1.0f / (float)(attn_len[b] - 1);
        for (int d = t; d < DD; d += 256) cv[d] = ctxsum[b * DD + d] * inv;
        __syncthreads();
        const float* wr = W_ctx + (size_t)j * DD;
        float acc = b_ctx[j];
        for (int d = 0; d < DD; ++d) acc += wr[d] * cv[d];
        out_rc[b * TT + j] = acc;
    }
}

// ---------- 4. GRU coop scan (R5 protocol + parallel poll + no-drain end barrier) ----------
// R5-exact tagged-pair protocol (known-good 402 us), two mechanical changes:
//  (a) the 24 poll loads are issued as PARALLEL inline-asm global_load_dwordx2
//      with sc0 sc1 (bypass L1+L2 -> MALL read = agent-load semantics; no
//      staleness possible) + ONE s_waitcnt vmcnt(0) + sched_barrier(0)
//      (rule #18). If __hip_atomic_load was serializing 24 x ~900cy MALL
//      round-trips per round, this collapses a round to ~one latency.
//  (b) end-of-step barrier is lgkmcnt(0) + s_barrier (no vmcnt drain): the
//      publish store's MALL ack drains inside the NEXT poll's vmcnt(0),
//      overlapped with poll latency instead of serialized before the barrier.
//      Induction safety unchanged: parity-slot WAW is ordered by the
//      poll-success chain; the barrier only protects hs (LDS).
__global__ __launch_bounds__(256, 1) void scan_coop_kernel(
        const float* __restrict__ gi,
        const float* __restrict__ Whf, const float* __restrict__ Whb,
        const float* __restrict__ bhhf, const float* __restrict__ bhhb,
        unsigned long long* __restrict__ hpair,  // [2 parity][2 dir][16 b][384]
        float* __restrict__ repac) {
    int wg = blockIdx.x;            // 0..47
    int dir = wg / NWPD;
    int w = wg % NWPD;
    int t = threadIdx.x;
    int kseg = t & 15, i_loc = t >> 4;
    int i_glob = w * 16 + i_loc;
    const float* Wh = dir ? Whb : Whf;

    // W fragments into registers (once); per-scalar asm pin keeps them resident
    float4 wr[3][6];
#pragma unroll
    for (int g = 0; g < 3; ++g)
#pragma unroll
        for (int j = 0; j < 6; ++j) {
            wr[g][j] = *(const float4*)(Wh + (size_t)(g * HH + i_glob) * HH + kseg * 4 + 64 * j);
            asm volatile("" : "+v"(wr[g][j].x), "+v"(wr[g][j].y),
                              "+v"(wr[g][j].z), "+v"(wr[g][j].w));
        }
    float bhn = (dir ? bhhb : bhhf)[2 * HH + i_glob];

    __shared__ __align__(16) float hs[6144];          // [16 b][384]
    float4* hs4 = (float4*)hs;

    for (int s = 0; s < 64; ++s) {
        int p = dir ? (63 - s) : s;
        // gi loads for this thread's output; issued before the poll
        const float* grow = gi + ((size_t)dir * 1024 + kseg * 64 + p) * G3;
        float g_r = grow[i_glob], g_z = grow[HH + i_glob], g_n = grow[2 * HH + i_glob];
        // ---- poll tagged pairs: 24 parallel MALL loads per round ----
        {
            const unsigned long long* src = hpair + (size_t)((s & 1) * 2 + dir) * 6144;
            unsigned int expect = (unsigned int)s;
            unsigned long long vals[24];
            for (;;) {
#pragma unroll
                for (int j = 0; j < 24; ++j) {
                    unsigned int off = (unsigned int)((j * 256 + t) * 8);
                    asm volatile("global_load_dwordx2 %0, %1, %2 sc0 sc1"
                                 : "=v"(vals[j]) : "v"(off), "s"(src));
                }
                asm volatile("s_waitcnt vmcnt(0)" ::: "memory");
                __builtin_amdgcn_sched_barrier(0);
                bool ok = true;
#pragma unroll
                for (int j = 0; j < 24; ++j) ok &= ((unsigned int)(vals[j] >> 32) == expect);
                if (ok) break;
                __builtin_amdgcn_s_sleep(1);
            }
#pragma unroll
            for (int j = 0; j < 24; ++j)
                hs[j * 256 + t] = __uint_as_float((unsigned int)vals[j]);
        }
        __syncthreads();
        // ---- partials for all 16 batches over this thread's k-set ----
        float pr[16], pz[16], pn[16];
#pragma unroll
        for (int b = 0; b < 16; ++b) {
            float4 hq[6];
#pragma unroll
            for (int j = 0; j < 6; ++j) hq[j] = hs4[b * 96 + kseg + 16 * j];
            float ar = 0.f, az = 0.f, an = 0.f;
#pragma unroll
            for (int j = 0; j < 6; ++j) {
                ar += wr[0][j].x * hq[j].x + wr[0][j].y * hq[j].y + wr[0][j].z * hq[j].z + wr[0][j].w * hq[j].w;
                az += wr[1][j].x * hq[j].x + wr[1][j].y * hq[j].y + wr[1][j].z * hq[j].z + wr[1][j].w * hq[j].w;
                an += wr[2][j].x * hq[j].x + wr[2][j].y * hq[j].y + wr[2][j].z * hq[j].z + wr[2][j].w * hq[j].w;
            }
            pr[b] = ar; pz[b] = az; pn[b] = an;
        }
        // ---- butterfly reduce across the 16 kseg lanes; end: b == kseg ----
        float qr[8], qz[8], qn[8];
        {
            const bool hi = (kseg & 8) != 0;
#pragma unroll
            for (int j = 0; j < 8; ++j) {
                float sr_ = hi ? pr[j] : pr[j + 8];
                qr[j] = (hi ? pr[j + 8] : pr[j]) + __shfl_xor(sr_, 8);
                float sz_ = hi ? pz[j] : pz[j + 8];
                qz[j] = (hi ? pz[j + 8] : pz[j]) + __shfl_xor(sz_, 8);
                float sn_ = hi ? pn[j] : pn[j + 8];
                qn[j] = (hi ? pn[j + 8] : pn[j]) + __shfl_xor(sn_, 8);
            }
        }
        float ur[4], uz[4], un[4];
        {
            const bool hi = (kseg & 4) != 0;
#pragma unroll
            for (int j = 0; j < 4; ++j) {
                float sr_ = hi ? qr[j] : qr[j + 4];
                ur[j] = (hi ? qr[j + 4] : qr[j]) + __shfl_xor(sr_, 4);
                float sz_ = hi ? qz[j] : qz[j + 4];
                uz[j] = (hi ? qz[j + 4] : qz[j]) + __shfl_xor(sz_, 4);
                float sn_ = hi ? qn[j] : qn[j + 4];
                un[j] = (hi ? qn[j + 4] : qn[j]) + __shfl_xor(sn_, 4);
            }
        }
        float vr[2], vz[2], vn[2];
        {
            const bool hi = (kseg & 2) != 0;
#pragma unroll
            for (int j = 0; j < 2; ++j) {
                float sr_ = hi ? ur[j] : ur[j + 2];
                vr[j] = (hi ? ur[j + 2] : ur[j]) + __shfl_xor(sr_, 2);
                float sz_ = hi ? uz[j] : uz[j + 2];
                vz[j] = (hi ? uz[j + 2] : uz[j]) + __shfl_xor(sz_, 2);
                float sn_ = hi ? un[j] : un[j + 2];
                vn[j] = (hi ? un[j + 2] : un[j]) + __shfl_xor(sn_, 2);
            }
        }
        float sr, sz, sn;
        {
            const bool hi = (kseg & 1) != 0;
            float sr_ = hi ? vr[0] : vr[1];
            sr = (hi ? vr[1] : vr[0]) + __shfl_xor(sr_, 1);
            float sz_ = hi ? vz[0] : vz[1];
            sz = (hi ? vz[1] : vz[0]) + __shfl_xor(sz_, 1);
            float sn_ = hi ? vn[0] : vn[1];
            sn = (hi ? vn[1] : vn[0]) + __shfl_xor(sn_, 1);
        }
        // ---- epilogue: every thread owns one (b = kseg, i_glob) output ----
        float r = 1.0f / (1.0f + expf(-(g_r + sr)));
        float z = 1.0f / (1.0f + expf(-(g_z + sz)));
        float n = tanhf(g_n + r * (sn + bhn));
        float hold = hs[kseg * 384 + i_glob];
        float hnew = (1.0f - z) * n + z * hold;
        // publish {tag = s+1, h} as one 8-byte relaxed agent store (fire-and-forget)
        unsigned long long pv = ((unsigned long long)(unsigned int)(s + 1) << 32)
                              | (unsigned long long)__float_as_uint(hnew);
        __hip_atomic_store(hpair + (size_t)(((s + 1) & 1) * 2 + dir) * 6144 + kseg * 384 + i_glob,
                           pv, __ATOMIC_RELAXED, __HIP_MEMORY_SCOPE_AGENT);
        repac[(size_t)(kseg * 64 + p) * TT + dir * HH + i_glob] = hnew;
        // end-of-step barrier: LDS-only (no vmcnt drain of the publish store)
        asm volatile("s_waitcnt lgkmcnt(0)" ::: "memory");
        __builtin_amdgcn_sched_barrier(0);
        __builtin_amdgcn_s_barrier();
    }
}

// ---------- 5. q and k dot products (one wave each, fp64 accumulation) ----------
__global__ void qkv_kernel(const float* __restrict__ repac,
                           const float* __restrict__ repctx,
                           const float* __restrict__ Wfind,
                           float* __restrict__ qv, float* __restrict__ kv) {
    int w = blockIdx.x * 4 + (threadIdx.x >> 6);
    int lane = threadIdx.x & 63;
    const float* row;
    const float* vec;
    float* dst;
    if (w < 1024) {
        row = repac + (size_t)w * TT;
        vec = Wfind;
        dst = qv + w;
    } else {
        int u = w - 1024;
        int b = u / 65, j = u % 65;
        row = (j < 64) ? (repac + (size_t)(b * 64 + j) * TT) : (repctx + (size_t)b * TT);
        vec = Wfind + TT;
        dst = kv + u;
    }
    double acc = 0.0;
    for (int d = lane; d < TT; d += 64) acc += (double)row[d] * (double)vec[d];
#pragma unroll
    for (int off = 32; off > 0; off >>= 1) acc += __shfl_down(acc, off);
    if (lane == 0) *dst = (float)acc;
}

// ---------- 6. top-k: fully-unrolled (sc[] in registers), one batch/block ----------
__global__ __launch_bounds__(64) void topk_kernel(
                            const float* __restrict__ qv,
                            const float* __restrict__ kv,
                            float* __restrict__ vals_out,
                            float* __restrict__ idx_out,
                            int* __restrict__ idxw) {
    int t = threadIdx.x;            // 0..63
    int b = blockIdx.x;             // batch
    int bs = b * 64 + t;
    __shared__ float kvs[65];
    for (int e = t; e < 65; e += 64) kvs[e] = kv[b * 65 + e];
    __syncthreads();
    float q = qv[bs];
    float sc[65];
#pragma unroll
    for (int j = 0; j < 65; ++j) {
        float x = q + kvs[j];                 // fp32 add, as np broadcast-add
        float e = (float)exp(-(double)x);     // ~correctly-rounded f32 exp
        sc[j] = 1.0f / (1.0f + e);            // fp32 add + fp32 divide, as np
    }
    unsigned long long taken = 0ull;
    bool tk64 = false;
    for (int kk = 0; kk < 8; ++kk) {
        float best = -3.0e38f;
        int bj = 0;
#pragma unroll
        for (int j = 0; j < 65; ++j) {
            bool tkn = (j < 64) ? (((taken >> j) & 1ull) != 0ull) : tk64;
            float v = sc[j];
            if (!tkn && v > best) { best = v; bj = j; }   // strict > => lowest index wins ties
        }
        if (bj < 64) taken |= (1ull << bj); else tk64 = true;
        vals_out[bs * 8 + kk] = best;
        idx_out[bs * 8 + kk] = (float)bj;
        idxw[bs * 8 + kk] = bj;
    }
}

// ---------- 7. v1 gather (float4) ----------
__global__ void v1_kernel(const float* __restrict__ repac,
                          const float* __restrict__ repctx,
                          const int* __restrict__ idxw,
                          float* __restrict__ v1) {
    int bs = blockIdx.x;
    int b = bs >> 6;
    int t = threadIdx.x;
    for (int kk = 0; kk < 8; ++kk) {
        int j = idxw[bs * 8 + kk];
        const float4* src = (const float4*)((j < 64) ? (repac + (size_t)(b * 64 + j) * TT)
                                                     : (repctx + (size_t)b * TT));
        float4* dst = (float4*)(v1 + ((size_t)bs * 8 + kk) * TT);
        for (int d = t; d < DD / 4; d += 256) dst[d] = src[d];
    }
}

extern "C" void kernel_launch(void* const* d_in, const int* in_sizes, int n_in,
                              void* d_out, int out_size, void* d_ws, size_t ws_size,
                              hipStream_t stream) {
    const float* hidden    = (const float*)d_in[0];
    const float* W_ih_f    = (const float*)d_in[1];
    const float* W_hh_f    = (const float*)d_in[2];
    const float* b_ih_f    = (const float*)d_in[3];
    const float* b_hh_f    = (const float*)d_in[4];
    const float* W_ih_b    = (const float*)d_in[5];
    const float* W_hh_b    = (const float*)d_in[6];
    const float* b_ih_b    = (const float*)d_in[7];
    const float* b_hh_b    = (const float*)d_in[8];
    const float* W_ctx     = (const float*)d_in[9];
    const float* b_ctx     = (const float*)d_in[10];
    const float* W_find    = (const float*)d_in[11];
    const int*   attn_len  = (const int*)d_in[12];
    const int*   span_start= (const int*)d_in[13];
    const int*   span_len  = (const int*)d_in[14];
    (void)in_sizes; (void)n_in; (void)out_size; (void)ws_size;

    // workspace layout (floats)
    float* ws   = (float*)d_ws;
    float* span = ws;                       // 786432
    float* gi   = span + 786432;            // 2359296
    float* ctx  = gi + 2359296;             // 12288
    float* qv   = ctx + 12288;              // 1024
    float* kv   = qv + 1024;                // 1040
    int*   idxw = (int*)(kv + 1040);        // 8192

    // output layout (floats)
    float* out      = (float*)d_out;
    float* o_repac  = out;                  // 786432
    float* o_repctx = out + 786432;         // 12288
    float* o_v1     = out + 798720;         // 6291456
    float* o_vals   = out + 7090176;        // 8192
    float* o_idx    = out + 7098368;        // 8192

    // hpair ALIASES the head of o_v1 (dead until v1_kernel fully overwrites
    // it). Zeroed every replay by fused_b_kernel's tail blocks.
    unsigned long long* hpair = (unsigned long long*)o_v1;

    // 7 nodes, zero memsets.
    span_mean_kernel<<<1024, 256, 0, stream>>>(hidden, span_start, span_len, span, ctx);
    ctx_accum_kernel<<<dim3(BB, 32), 256, 0, stream>>>(hidden, attn_len, ctx);
    fused_b_kernel<<<624, 256, 0, stream>>>(span, W_ih_f, W_ih_b,
                                            b_ih_f, b_hh_f, b_ih_b, b_hh_b, gi,
                                            ctx, attn_len, W_ctx, b_ctx,
                                            o_repctx, hpair);
    scan_coop_kernel<<<48, 256, 0, stream>>>(gi, W_hh_f, W_hh_b, b_hh_f, b_hh_b,
                                             hpair, o_repac);
    qkv_kernel<<<516, 256, 0, stream>>>(o_repac, o_repctx, W_find, qv, kv);
    topk_kernel<<<16, 64, 0, stream>>>(qv, kv, o_vals, o_idx, idxw);
    v1_kernel<<<1024, 256, 0, stream>>>(o_repac, o_repctx, idxw, o_v1);
}